// Round 17
// baseline (645.627 us; speedup 1.0000x reference)
//
#include <hip/hip_runtime.h>
#include <hip/hip_bf16.h>

// AtomicScaleModule — CGCNN GNN forward, MFMA bf16 activations x split-bf16
// weights. Lean bf16 pipeline (R14/R16): gather-first, no fences, bf16 A/S/T,
// A+S in-place, T ping-pong, bf16 u16 transpose slab.
// Delta vs R16: mid denses + embed use 2 GROUPS (32 atoms) per wave at
// (256,3): halved per-wave state fits 3 waves/SIMD WITHOUT spilling (R15's
// (256,3) spilled because 4-group state needs >170 VGPR). Gather is
// L3-latency-bound (T=38.4MB >> 4MB L2/XCD): more waves + shorter chains.
// FX kernel stays 4-group (256,2) (fat tail, runs once).
//   a = X@AE + ae_b
//   per layer: s = a@MW1[0:64]+b1 ; t = a@MW1[64:128]   (fused into producer)
//              H = sum_c relu(s + t[idx])               (gather @ head of dense)
//              agg = H@MW2 + 12*b2
//              u1 = relu(a@UW1[0:64] + agg@UW1[64:128] + ub1)
//              a' = relu(a + u1@UW2 + ub2)  (+ fused s,t of next layer)
//   af = relu(a@FX1+fb1)@FX2+fb2 ; props = af@PW^T+pb   (fused into last dense)
// nbr_fea / ne_w / ne_b dead.

constexpr int NA = 300000;
constexpr int SC2 = 38;    // 2-group slab: 2 x 18 u16 cols + 2 pad (row 76B)
constexpr int SC4 = 74;    // 4-group slab: 4 x 18 u16 cols + 2 pad (row 148B)

typedef short          s16x8 __attribute__((ext_vector_type(8)));
typedef float          f32x4 __attribute__((ext_vector_type(4)));
typedef unsigned short u16;

#define DEVFN static __device__ __forceinline__

DEVFN u16 f2bf(float x) {
  unsigned u = __float_as_uint(x);
  u += 0x7fffu + ((u >> 16) & 1u);          // RTNE
  return (u16)(u >> 16);
}
DEVFN float bf2f(u16 h) { return __uint_as_float(((unsigned)h) << 16); }

DEVFN s16x8 mk_hi(const float* v) {
  s16x8 hi;
#pragma unroll
  for (int i = 0; i < 8; i += 2) {
    __hip_bfloat162 h2 = __float22bfloat162_rn(make_float2(v[i], v[i + 1]));
    hi[i]     = (short)__bfloat16_as_ushort(h2.x);
    hi[i + 1] = (short)__bfloat16_as_ushort(h2.y);
  }
  return hi;
}

DEVFN f32x4 mf2(s16x8 ah, s16x8 bh, s16x8 bl, f32x4 c) {
  c = __builtin_amdgcn_mfma_f32_16x16x32_bf16(ah, bl, c, 0, 0, 0);
  c = __builtin_amdgcn_mfma_f32_16x16x32_bf16(ah, bh, c, 0, 0, 0);
  return c;
}

DEVFN void ldB(const u16* __restrict__ WH, const u16* __restrict__ WL,
               int seg, int kt, int ct, int CT, int l, s16x8& bh, s16x8& bl) {
  size_t o = (size_t)seg + ((size_t)((kt * CT + ct) * 64 + l)) * 8;
  bh = *(const s16x8*)(WH + o);
  bl = *(const s16x8*)(WL + o);
}

DEVFN f32x4 bias4(float bv) { f32x4 c; c[0] = bv; c[1] = bv; c[2] = bv; c[3] = bv; return c; }

// ==================== 2-group machinery (mid denses, embed) ================
DEVFN void stage_mm2g(const u16* __restrict__ WH, const u16* __restrict__ WL,
                      int seg, int kt0, const s16x8 (&fh)[2][2],
                      int l, f32x4 (&cc)[2][4]) {
#pragma unroll
  for (int ct = 0; ct < 4; ++ct)
#pragma unroll
    for (int kt = 0; kt < 2; ++kt) {
      s16x8 bh, bl; ldB(WH, WL, seg, kt0 + kt, ct, 4, l, bh, bl);
#pragma unroll
      for (int gr = 0; gr < 2; ++gr)
        cc[gr][ct] = mf2(fh[gr][kt], bh, bl, cc[gr][ct]);
    }
}

DEVFN void put_half_2g(u16 (*sl)[SC2], int m, int g, const f32x4 (&cc)[2][4], int h) {
#pragma unroll
  for (int gr = 0; gr < 2; ++gr)
#pragma unroll
    for (int c = 0; c < 2; ++c) {
      f32x4 v = cc[gr][2 * h + c];
      __hip_bfloat162 p0 = __float22bfloat162_rn(make_float2(v[0], v[1]));
      __hip_bfloat162 p1 = __float22bfloat162_rn(make_float2(v[2], v[3]));
      u16* p = &sl[16 * c + m][gr * 18 + 4 * g];
      p[0] = __bfloat16_as_ushort(p0.x);
      p[1] = __bfloat16_as_ushort(p0.y);
      p[2] = __bfloat16_as_ushort(p1.x);
      p[3] = __bfloat16_as_ushort(p1.y);
    }
}
DEVFN s16x8 get_frag_2g(const u16 (*sl)[SC2], int m, int g, int gr) {
  s16x8 f;
#pragma unroll
  for (int i = 0; i < 8; ++i) f[i] = (short)sl[8 * g + i][gr * 18 + m];
  return f;
}
DEVFN void get_half_f32_2g(const u16 (*sl)[SC2], int m, int g, int gr, float* v) {
#pragma unroll
  for (int i = 0; i < 8; ++i) v[i] = bf2f(sl[8 * g + i][gr * 18 + m]);
}
DEVFN void trans_frags_2g(u16 (*sl)[SC2], int m, int g, const f32x4 (&cc)[2][4],
                          s16x8 (&fh)[2][2]) {
#pragma unroll
  for (int h = 0; h < 2; ++h) {
    put_half_2g(sl, m, g, cc, h);
#pragma unroll
    for (int gr = 0; gr < 2; ++gr) fh[gr][h] = get_frag_2g(sl, m, g, gr);
  }
}
DEVFN void trans_store_2g(u16 (*sl)[SC2], int m, int g, const f32x4 (&cc)[2][4],
                          u16* __restrict__ B, const int (&nat)[2], const bool (&ok)[2]) {
#pragma unroll
  for (int h = 0; h < 2; ++h) {
    put_half_2g(sl, m, g, cc, h);
#pragma unroll
    for (int gr = 0; gr < 2; ++gr) {
      if (!ok[gr]) continue;
      int col = gr * 18 + m;
      uint4 q;
      unsigned* qp = (unsigned*)&q;
#pragma unroll
      for (int j = 0; j < 4; ++j)
        qp[j] = (unsigned)sl[8 * g + 2 * j][col] | ((unsigned)sl[8 * g + 2 * j + 1][col] << 16);
      *(uint4*)(B + (size_t)nat[gr] * 64 + 32 * h + 8 * g) = q;
    }
  }
}

// ==================== 4-group machinery (FX kernel only) ===================
DEVFN void stage_mm4g(const u16* __restrict__ WH, const u16* __restrict__ WL,
                      int seg, int kt0, const s16x8 (&fh)[4][2],
                      int l, f32x4 (&cc)[4][4]) {
#pragma unroll
  for (int ct = 0; ct < 4; ++ct)
#pragma unroll
    for (int kt = 0; kt < 2; ++kt) {
      s16x8 bh, bl; ldB(WH, WL, seg, kt0 + kt, ct, 4, l, bh, bl);
#pragma unroll
      for (int gr = 0; gr < 4; ++gr)
        cc[gr][ct] = mf2(fh[gr][kt], bh, bl, cc[gr][ct]);
    }
}
DEVFN void put_half_4g(u16 (*sl)[SC4], int m, int g, const f32x4 (&cc)[4][4], int h) {
#pragma unroll
  for (int gr = 0; gr < 4; ++gr)
#pragma unroll
    for (int c = 0; c < 2; ++c) {
      f32x4 v = cc[gr][2 * h + c];
      __hip_bfloat162 p0 = __float22bfloat162_rn(make_float2(v[0], v[1]));
      __hip_bfloat162 p1 = __float22bfloat162_rn(make_float2(v[2], v[3]));
      u16* p = &sl[16 * c + m][gr * 18 + 4 * g];
      p[0] = __bfloat16_as_ushort(p0.x);
      p[1] = __bfloat16_as_ushort(p0.y);
      p[2] = __bfloat16_as_ushort(p1.x);
      p[3] = __bfloat16_as_ushort(p1.y);
    }
}
DEVFN s16x8 get_frag_4g(const u16 (*sl)[SC4], int m, int g, int gr) {
  s16x8 f;
#pragma unroll
  for (int i = 0; i < 8; ++i) f[i] = (short)sl[8 * g + i][gr * 18 + m];
  return f;
}
DEVFN void get_half_f32_4g(const u16 (*sl)[SC4], int m, int g, int gr, float* v) {
#pragma unroll
  for (int i = 0; i < 8; ++i) v[i] = bf2f(sl[8 * g + i][gr * 18 + m]);
}
DEVFN void trans_frags_4g(u16 (*sl)[SC4], int m, int g, const f32x4 (&cc)[4][4],
                          s16x8 (&fh)[4][2]) {
#pragma unroll
  for (int h = 0; h < 2; ++h) {
    put_half_4g(sl, m, g, cc, h);
#pragma unroll
    for (int gr = 0; gr < 4; ++gr) fh[gr][h] = get_frag_4g(sl, m, g, gr);
  }
}

DEVFN void pack_store8(u16* __restrict__ p, const float* v) {
  uint4 q;
  unsigned* qp = (unsigned*)&q;
#pragma unroll
  for (int i = 0; i < 4; ++i)
    qp[i] = (unsigned)f2bf(v[2 * i]) | ((unsigned)f2bf(v[2 * i + 1]) << 16);
  *(uint4*)p = q;
}

// ---- weight pre-conversion to B-frag layout (hi/lo bf16) ------------------
__global__ __launch_bounds__(256) void k_prep(
    const float* __restrict__ ae, const float* __restrict__ mw1,
    const float* __restrict__ mw2, const float* __restrict__ uw1,
    const float* __restrict__ uw2, const float* __restrict__ fx1,
    const float* __restrict__ fx2,
    u16* __restrict__ WH, u16* __restrict__ WL) {
  int e = blockIdx.x * 256 + threadIdx.x;
  const float* src;
  int K, N, loc;
  if (e < 6144) { src = ae; K = 92; N = 64; loc = e; }
  else if (e < 79872) {
    int r = e - 6144;
    int lyr = r / 24576, q = r % 24576;
    size_t l64 = (size_t)lyr * 64;
    if (q < 8192)       { src = mw1 + l64 * 128; K = 128; N = 64; loc = q; }
    else if (q < 12288) { src = mw2 + l64 * 64;  K = 64;  N = 64; loc = q - 8192; }
    else if (q < 20480) { src = uw1 + l64 * 128; K = 128; N = 64; loc = q - 12288; }
    else                { src = uw2 + l64 * 64;  K = 64;  N = 64; loc = q - 20480; }
  }
  else if (e < 88064) { src = fx1; K = 64;  N = 128; loc = e - 79872; }
  else if (e < 96256) { src = fx2; K = 128; N = 64;  loc = e - 88064; }
  else return;
  int k = (N == 64) ? (loc >> 6) : (loc >> 7);
  int j = loc & (N - 1);
  float v = (k < K) ? src[(size_t)k * N + j] : 0.f;
  u16 h = f2bf(v);
  int CT = N >> 4;
  int lane = ((k >> 3) & 3) * 16 + (j & 15);
  int fidx = (e - loc) + (((k >> 5) * CT + (j >> 4)) * 64 + lane) * 8 + (k & 7);
  WH[fidx] = h;
  WL[fidx] = f2bf(v - bf2f(h));
}

// ---- embed + s,t of layer 0 (32 atoms per wave, (256,3)) ------------------
__global__ __launch_bounds__(256, 3) void k_embed_st(
    const float* __restrict__ X,
    const u16* __restrict__ WH, const u16* __restrict__ WL,
    const float* __restrict__ aeb, const float* __restrict__ b1,
    u16* __restrict__ A, u16* __restrict__ S, u16* __restrict__ T) {
  __shared__ u16 slab[4][32][SC2];
  int w = threadIdx.x >> 6, l = threadIdx.x & 63, m = l & 15, g = l >> 4;
  u16 (*sl)[SC2] = slab[w];
  int nbase = blockIdx.x * 128 + w * 32;
  int nat[2]; bool ok[2];
#pragma unroll
  for (int gr = 0; gr < 2; ++gr) {
    nat[gr] = nbase + gr * 16 + m;
    ok[gr] = nat[gr] < NA;
    if (!ok[gr]) nat[gr] = NA - 1;
  }

  f32x4 ca[2][4];
#pragma unroll
  for (int gr = 0; gr < 2; ++gr)
#pragma unroll
    for (int ct = 0; ct < 4; ++ct) ca[gr][ct] = bias4(aeb[16 * ct + m]);
#pragma unroll
  for (int kt = 0; kt < 3; ++kt) {
    s16x8 xh[2];
#pragma unroll
    for (int gr = 0; gr < 2; ++gr) {
      const float* xr = X + (size_t)nat[gr] * 92;
      float v[8];
      if (kt < 2) {
        f32x4 a = *(const f32x4*)(xr + kt * 32 + g * 8);
        f32x4 b = *(const f32x4*)(xr + kt * 32 + g * 8 + 4);
        v[0]=a[0]; v[1]=a[1]; v[2]=a[2]; v[3]=a[3]; v[4]=b[0]; v[5]=b[1]; v[6]=b[2]; v[7]=b[3];
      } else if (g < 3) {
        f32x4 a = *(const f32x4*)(xr + 64 + g * 8);
        f32x4 b = *(const f32x4*)(xr + 64 + g * 8 + 4);
        v[0]=a[0]; v[1]=a[1]; v[2]=a[2]; v[3]=a[3]; v[4]=b[0]; v[5]=b[1]; v[6]=b[2]; v[7]=b[3];
      } else {
        f32x4 a = *(const f32x4*)(xr + 88);
        v[0]=a[0]; v[1]=a[1]; v[2]=a[2]; v[3]=a[3]; v[4]=0.f; v[5]=0.f; v[6]=0.f; v[7]=0.f;
      }
      xh[gr] = mk_hi(v);
    }
#pragma unroll
    for (int ct = 0; ct < 4; ++ct) {
      s16x8 bh, bl; ldB(WH, WL, 0, kt, ct, 4, l, bh, bl);
#pragma unroll
      for (int gr = 0; gr < 2; ++gr)
        ca[gr][ct] = mf2(xh[gr], bh, bl, ca[gr][ct]);
    }
  }

  // transpose a0: store A (bf16) + fragments from same u16 reads
  s16x8 ah[2][2];
#pragma unroll
  for (int h = 0; h < 2; ++h) {
    put_half_2g(sl, m, g, ca, h);
#pragma unroll
    for (int gr = 0; gr < 2; ++gr) {
      int col = gr * 18 + m;
      u16 t8[8];
#pragma unroll
      for (int i = 0; i < 8; ++i) t8[i] = sl[8 * g + i][col];
      if (ok[gr]) {
        uint4 q;
        unsigned* qp = (unsigned*)&q;
#pragma unroll
        for (int j = 0; j < 4; ++j)
          qp[j] = (unsigned)t8[2 * j] | ((unsigned)t8[2 * j + 1] << 16);
        *(uint4*)(A + (size_t)nat[gr] * 64 + 32 * h + 8 * g) = q;
      }
      s16x8 f;
#pragma unroll
      for (int i = 0; i < 8; ++i) f[i] = (short)t8[i];
      ah[gr][h] = f;
    }
  }

  // s = a0@MW1[0:64] + b1
  f32x4 cs[2][4];
#pragma unroll
  for (int gr = 0; gr < 2; ++gr)
#pragma unroll
    for (int ct = 0; ct < 4; ++ct) cs[gr][ct] = bias4(b1[16 * ct + m]);
  stage_mm2g(WH, WL, 6144, 0, ah, l, cs);
  trans_store_2g(sl, m, g, cs, S, nat, ok);

  // t = a0@MW1[64:128]
  f32x4 cT[2][4];
#pragma unroll
  for (int gr = 0; gr < 2; ++gr)
#pragma unroll
    for (int ct = 0; ct < 4; ++ct) cT[gr][ct] = bias4(0.f);
  stage_mm2g(WH, WL, 6144, 2, ah, l, cT);
  trans_store_2g(sl, m, g, cT, T, nat, ok);
}

// ---- mid dense: gather + chain + next-layer s,t (2 groups, (256,3)) -------
__global__ __launch_bounds__(256, 3) void k_dense_mid(
    u16* __restrict__ A, u16* __restrict__ S,
    const u16* __restrict__ T, const int* __restrict__ IDX,
    const u16* __restrict__ WH, const u16* __restrict__ WL,
    int segW2, int segU1, int segU2, int segWn,
    const float* __restrict__ b2, const float* __restrict__ ub1,
    const float* __restrict__ ub2, const float* __restrict__ bn,
    u16* __restrict__ Tout) {
  __shared__ u16 slab[4][32][SC2];
  int w = threadIdx.x >> 6, l = threadIdx.x & 63, m = l & 15, g = l >> 4;
  u16 (*sl)[SC2] = slab[w];
  int nbase = blockIdx.x * 128 + w * 32;
  int nat[2]; bool ok[2];
#pragma unroll
  for (int gr = 0; gr < 2; ++gr) {
    nat[gr] = nbase + gr * 16 + m;
    ok[gr] = nat[gr] < NA;
    if (!ok[gr]) nat[gr] = NA - 1;
  }

  // A-row fragments at entry (fly under gather; reused for u1 + residual)
  s16x8 arh[2][2];
#pragma unroll
  for (int gr = 0; gr < 2; ++gr)
#pragma unroll
    for (int kt = 0; kt < 2; ++kt)
      arh[gr][kt] = *(const s16x8*)(A + (size_t)nat[gr] * 64 + kt * 32 + g * 8);

  // gather: H = sum_c relu(s + t[idx])
  s16x8 hh[2][2];
#pragma unroll
  for (int gr = 0; gr < 2; ++gr) {
    const int* ip = IDX + (size_t)nat[gr] * 12;
    int4 i0 = *(const int4*)ip;
    int4 i1 = *(const int4*)(ip + 4);
    int4 i2 = *(const int4*)(ip + 8);
    int idxs[12] = {i0.x, i0.y, i0.z, i0.w, i1.x, i1.y, i1.z, i1.w,
                    i2.x, i2.y, i2.z, i2.w};
#pragma unroll
    for (int kt = 0; kt < 2; ++kt) {
      int f0 = 32 * kt + 8 * g;
      uint4 sv4 = *(const uint4*)(S + (size_t)nat[gr] * 64 + f0);
      float sv[8] = {
        bf2f((u16)(sv4.x & 0xffff)), bf2f((u16)(sv4.x >> 16)),
        bf2f((u16)(sv4.y & 0xffff)), bf2f((u16)(sv4.y >> 16)),
        bf2f((u16)(sv4.z & 0xffff)), bf2f((u16)(sv4.z >> 16)),
        bf2f((u16)(sv4.w & 0xffff)), bf2f((u16)(sv4.w >> 16))};
      float ha[8] = {0, 0, 0, 0, 0, 0, 0, 0};
#pragma unroll
      for (int c = 0; c < 12; ++c) {
        uint4 tv = *(const uint4*)(T + (size_t)idxs[c] * 64 + f0);
        ha[0] += fmaxf(sv[0] + bf2f((u16)(tv.x & 0xffff)), 0.f);
        ha[1] += fmaxf(sv[1] + bf2f((u16)(tv.x >> 16)), 0.f);
        ha[2] += fmaxf(sv[2] + bf2f((u16)(tv.y & 0xffff)), 0.f);
        ha[3] += fmaxf(sv[3] + bf2f((u16)(tv.y >> 16)), 0.f);
        ha[4] += fmaxf(sv[4] + bf2f((u16)(tv.z & 0xffff)), 0.f);
        ha[5] += fmaxf(sv[5] + bf2f((u16)(tv.z >> 16)), 0.f);
        ha[6] += fmaxf(sv[6] + bf2f((u16)(tv.w & 0xffff)), 0.f);
        ha[7] += fmaxf(sv[7] + bf2f((u16)(tv.w >> 16)), 0.f);
      }
      hh[gr][kt] = mk_hi(ha);
    }
  }

  // agg = H@W2 + 12*b2
  f32x4 cg[2][4];
#pragma unroll
  for (int gr = 0; gr < 2; ++gr)
#pragma unroll
    for (int ct = 0; ct < 4; ++ct) cg[gr][ct] = bias4(12.f * b2[16 * ct + m]);
  stage_mm2g(WH, WL, segW2, 0, hh, l, cg);

  // u1 = relu(a@U1[0:64] + agg@U1[64:128] + ub1)
  f32x4 cu[2][4];
#pragma unroll
  for (int gr = 0; gr < 2; ++gr)
#pragma unroll
    for (int ct = 0; ct < 4; ++ct) cu[gr][ct] = bias4(ub1[16 * ct + m]);
  stage_mm2g(WH, WL, segU1, 0, arh, l, cu);
  {
    s16x8 qh[2][2];
    trans_frags_2g(sl, m, g, cg, qh);
    stage_mm2g(WH, WL, segU1, 2, qh, l, cu);
  }
#pragma unroll
  for (int gr = 0; gr < 2; ++gr)
#pragma unroll
    for (int ct = 0; ct < 4; ++ct)
#pragma unroll
      for (int r = 0; r < 4; ++r) cu[gr][ct][r] = fmaxf(cu[gr][ct][r], 0.f);

  // upd = u1@U2 + ub2
  f32x4 cd[2][4];
#pragma unroll
  for (int gr = 0; gr < 2; ++gr)
#pragma unroll
    for (int ct = 0; ct < 4; ++ct) cd[gr][ct] = bias4(ub2[16 * ct + m]);
  {
    s16x8 uh[2][2];
    trans_frags_2g(sl, m, g, cu, uh);
    stage_mm2g(WH, WL, segU2, 0, uh, l, cd);
  }

  // a' = relu(a + upd): residual from held arh, store bf16 in-place
  s16x8 anh[2][2];
#pragma unroll
  for (int h = 0; h < 2; ++h) {
    put_half_2g(sl, m, g, cd, h);
#pragma unroll
    for (int gr = 0; gr < 2; ++gr) {
      float v[8];
      get_half_f32_2g(sl, m, g, gr, v);
#pragma unroll
      for (int i = 0; i < 8; ++i)
        v[i] = fmaxf(v[i] + bf2f((u16)arh[gr][h][i]), 0.f);
      if (ok[gr]) pack_store8(A + (size_t)nat[gr] * 64 + 32 * h + 8 * g, v);
      anh[gr][h] = mk_hi(v);
    }
  }

  // s_next (in-place over S)
  f32x4 cs[2][4];
#pragma unroll
  for (int gr = 0; gr < 2; ++gr)
#pragma unroll
    for (int ct = 0; ct < 4; ++ct) cs[gr][ct] = bias4(bn[16 * ct + m]);
  stage_mm2g(WH, WL, segWn, 0, anh, l, cs);
  trans_store_2g(sl, m, g, cs, S, nat, ok);

  // t_next (ping-pong)
  f32x4 cT[2][4];
#pragma unroll
  for (int gr = 0; gr < 2; ++gr)
#pragma unroll
    for (int ct = 0; ct < 4; ++ct) cT[gr][ct] = bias4(0.f);
  stage_mm2g(WH, WL, segWn, 2, anh, l, cT);
  trans_store_2g(sl, m, g, cT, Tout, nat, ok);
}

// ---- last dense + fx tail (4 groups, (256,2)) -----------------------------
__global__ __launch_bounds__(256, 2) void k_dense_fx(
    u16* __restrict__ A, u16* __restrict__ S,
    const u16* __restrict__ T, const int* __restrict__ IDX,
    const u16* __restrict__ WH, const u16* __restrict__ WL,
    int segW2, int segU1, int segU2,
    const float* __restrict__ b2, const float* __restrict__ ub1,
    const float* __restrict__ ub2,
    const float* __restrict__ fb1, const float* __restrict__ fb2,
    const float* __restrict__ PW, const float* __restrict__ PB,
    float* __restrict__ RawOut, float* __restrict__ AF, float* __restrict__ PR) {
  __shared__ u16 slab[4][32][SC4];
  int w = threadIdx.x >> 6, l = threadIdx.x & 63, m = l & 15, g = l >> 4;
  u16 (*sl)[SC4] = slab[w];
  int nbase = blockIdx.x * 256 + w * 64;
  int nat[4]; bool ok[4];
#pragma unroll
  for (int gr = 0; gr < 4; ++gr) {
    nat[gr] = nbase + gr * 16 + m;
    ok[gr] = nat[gr] < NA;
    if (!ok[gr]) nat[gr] = NA - 1;
  }

  s16x8 arh[4][2];
#pragma unroll
  for (int gr = 0; gr < 4; ++gr)
#pragma unroll
    for (int kt = 0; kt < 2; ++kt)
      arh[gr][kt] = *(const s16x8*)(A + (size_t)nat[gr] * 64 + kt * 32 + g * 8);

  s16x8 hh[4][2];
#pragma unroll
  for (int gr = 0; gr < 4; ++gr) {
    const int* ip = IDX + (size_t)nat[gr] * 12;
    int4 i0 = *(const int4*)ip;
    int4 i1 = *(const int4*)(ip + 4);
    int4 i2 = *(const int4*)(ip + 8);
    int idxs[12] = {i0.x, i0.y, i0.z, i0.w, i1.x, i1.y, i1.z, i1.w,
                    i2.x, i2.y, i2.z, i2.w};
#pragma unroll
    for (int kt = 0; kt < 2; ++kt) {
      int f0 = 32 * kt + 8 * g;
      uint4 sv4 = *(const uint4*)(S + (size_t)nat[gr] * 64 + f0);
      float sv[8] = {
        bf2f((u16)(sv4.x & 0xffff)), bf2f((u16)(sv4.x >> 16)),
        bf2f((u16)(sv4.y & 0xffff)), bf2f((u16)(sv4.y >> 16)),
        bf2f((u16)(sv4.z & 0xffff)), bf2f((u16)(sv4.z >> 16)),
        bf2f((u16)(sv4.w & 0xffff)), bf2f((u16)(sv4.w >> 16))};
      float ha[8] = {0, 0, 0, 0, 0, 0, 0, 0};
#pragma unroll
      for (int c = 0; c < 12; ++c) {
        uint4 tv = *(const uint4*)(T + (size_t)idxs[c] * 64 + f0);
        ha[0] += fmaxf(sv[0] + bf2f((u16)(tv.x & 0xffff)), 0.f);
        ha[1] += fmaxf(sv[1] + bf2f((u16)(tv.x >> 16)), 0.f);
        ha[2] += fmaxf(sv[2] + bf2f((u16)(tv.y & 0xffff)), 0.f);
        ha[3] += fmaxf(sv[3] + bf2f((u16)(tv.y >> 16)), 0.f);
        ha[4] += fmaxf(sv[4] + bf2f((u16)(tv.z & 0xffff)), 0.f);
        ha[5] += fmaxf(sv[5] + bf2f((u16)(tv.z >> 16)), 0.f);
        ha[6] += fmaxf(sv[6] + bf2f((u16)(tv.w & 0xffff)), 0.f);
        ha[7] += fmaxf(sv[7] + bf2f((u16)(tv.w >> 16)), 0.f);
      }
      hh[gr][kt] = mk_hi(ha);
    }
  }

  f32x4 cg[4][4];
#pragma unroll
  for (int gr = 0; gr < 4; ++gr)
#pragma unroll
    for (int ct = 0; ct < 4; ++ct) cg[gr][ct] = bias4(12.f * b2[16 * ct + m]);
  stage_mm4g(WH, WL, segW2, 0, hh, l, cg);

  f32x4 cu[4][4];
#pragma unroll
  for (int gr = 0; gr < 4; ++gr)
#pragma unroll
    for (int ct = 0; ct < 4; ++ct) cu[gr][ct] = bias4(ub1[16 * ct + m]);
  stage_mm4g(WH, WL, segU1, 0, arh, l, cu);
  {
    s16x8 qh[4][2];
    trans_frags_4g(sl, m, g, cg, qh);
    stage_mm4g(WH, WL, segU1, 2, qh, l, cu);
  }
#pragma unroll
  for (int gr = 0; gr < 4; ++gr)
#pragma unroll
    for (int ct = 0; ct < 4; ++ct)
#pragma unroll
      for (int r = 0; r < 4; ++r) cu[gr][ct][r] = fmaxf(cu[gr][ct][r], 0.f);

  f32x4 cd[4][4];
#pragma unroll
  for (int gr = 0; gr < 4; ++gr)
#pragma unroll
    for (int ct = 0; ct < 4; ++ct) cd[gr][ct] = bias4(ub2[16 * ct + m]);
  {
    s16x8 uh[4][2];
    trans_frags_4g(sl, m, g, cu, uh);
    stage_mm4g(WH, WL, segU2, 0, uh, l, cd);
  }

  // raw = relu(a + upd) -> f32 RawOut + fragments
  s16x8 anh[4][2];
#pragma unroll
  for (int h = 0; h < 2; ++h) {
    put_half_4g(sl, m, g, cd, h);
#pragma unroll
    for (int gr = 0; gr < 4; ++gr) {
      float v[8];
      get_half_f32_4g(sl, m, g, gr, v);
#pragma unroll
      for (int i = 0; i < 8; ++i)
        v[i] = fmaxf(v[i] + bf2f((u16)arh[gr][h][i]), 0.f);
      if (ok[gr]) {
        float* p = RawOut + (size_t)nat[gr] * 64 + 32 * h + 8 * g;
        *(float4*)p = make_float4(v[0], v[1], v[2], v[3]);
        *(float4*)(p + 4) = make_float4(v[4], v[5], v[6], v[7]);
      }
      anh[gr][h] = mk_hi(v);
    }
  }

  // af = relu(raw@FX1+fb1)@FX2+fb2, hidden 128 in two 64-col rounds
  f32x4 cf[4][4];
#pragma unroll
  for (int gr = 0; gr < 4; ++gr)
#pragma unroll
    for (int ct = 0; ct < 4; ++ct) cf[gr][ct] = bias4(fb2[16 * ct + m]);

#pragma unroll
  for (int hr = 0; hr < 2; ++hr) {
    f32x4 chh[4][4];
#pragma unroll
    for (int gr = 0; gr < 4; ++gr)
#pragma unroll
      for (int ct = 0; ct < 4; ++ct)
        chh[gr][ct] = bias4(fb1[16 * (4 * hr + ct) + m]);
#pragma unroll
    for (int ct = 0; ct < 4; ++ct)
#pragma unroll
      for (int kt = 0; kt < 2; ++kt) {
        s16x8 bh, bl; ldB(WH, WL, 79872, kt, 4 * hr + ct, 8, l, bh, bl);
#pragma unroll
        for (int gr = 0; gr < 4; ++gr)
          chh[gr][ct] = mf2(anh[gr][kt], bh, bl, chh[gr][ct]);
      }
#pragma unroll
    for (int gr = 0; gr < 4; ++gr)
#pragma unroll
      for (int ct = 0; ct < 4; ++ct)
#pragma unroll
        for (int r = 0; r < 4; ++r) chh[gr][ct][r] = fmaxf(chh[gr][ct][r], 0.f);

    s16x8 hfh[4][2];
    trans_frags_4g(sl, m, g, chh, hfh);
    stage_mm4g(WH, WL, 88064, 2 * hr, hfh, l, cf);
  }

  // AF store + props partials in the same A-layout pass
  float pp[4][4];
#pragma unroll
  for (int gr = 0; gr < 4; ++gr)
#pragma unroll
    for (int p = 0; p < 4; ++p) pp[gr][p] = 0.f;
#pragma unroll
  for (int h = 0; h < 2; ++h) {
    put_half_4g(sl, m, g, cf, h);
    f32x4 pw0[4], pw1[4];
#pragma unroll
    for (int p = 0; p < 4; ++p) {
      const float* q = PW + p * 64 + 32 * h + 8 * g;
      pw0[p] = *(const f32x4*)q;
      pw1[p] = *(const f32x4*)(q + 4);
    }
#pragma unroll
    for (int gr = 0; gr < 4; ++gr) {
      float v[8];
      get_half_f32_4g(sl, m, g, gr, v);
      if (ok[gr]) {
        float* p = AF + (size_t)nat[gr] * 64 + 32 * h + 8 * g;
        *(float4*)p = make_float4(v[0], v[1], v[2], v[3]);
        *(float4*)(p + 4) = make_float4(v[4], v[5], v[6], v[7]);
      }
#pragma unroll
      for (int p = 0; p < 4; ++p)
#pragma unroll
        for (int i = 0; i < 4; ++i)
          pp[gr][p] += v[i] * pw0[p][i] + v[i + 4] * pw1[p][i];
    }
  }
#pragma unroll
  for (int gr = 0; gr < 4; ++gr) {
    float r0 = pp[gr][0], r1 = pp[gr][1], r2 = pp[gr][2], r3 = pp[gr][3];
    r0 += __shfl_xor(r0, 16); r0 += __shfl_xor(r0, 32);
    r1 += __shfl_xor(r1, 16); r1 += __shfl_xor(r1, 32);
    r2 += __shfl_xor(r2, 16); r2 += __shfl_xor(r2, 32);
    r3 += __shfl_xor(r3, 16); r3 += __shfl_xor(r3, 32);
    float sel = (g == 0) ? r0 : (g == 1) ? r1 : (g == 2) ? r2 : r3;
    if (ok[gr]) PR[(size_t)nat[gr] * 4 + g] = sel + PB[g];
  }
}

extern "C" void kernel_launch(void* const* d_in, const int* in_sizes, int n_in,
                              void* d_out, int out_size, void* d_ws, size_t ws_size,
                              hipStream_t stream) {
  const float* atom_fea = (const float*)d_in[0];
  const int*   nbr_idx  = (const int*)d_in[2];
  const float* ae_w   = (const float*)d_in[3];
  const float* ae_b   = (const float*)d_in[4];
  const float* msg_w1 = (const float*)d_in[7];
  const float* msg_b1 = (const float*)d_in[8];
  const float* msg_w2 = (const float*)d_in[9];
  const float* msg_b2 = (const float*)d_in[10];
  const float* upd_w1 = (const float*)d_in[11];
  const float* upd_b1 = (const float*)d_in[12];
  const float* upd_w2 = (const float*)d_in[13];
  const float* upd_b2 = (const float*)d_in[14];
  const float* fx_w1  = (const float*)d_in[15];
  const float* fx_b1  = (const float*)d_in[16];
  const float* fx_w2  = (const float*)d_in[17];
  const float* fx_b2  = (const float*)d_in[18];
  const float* prop_w = (const float*)d_in[19];
  const float* prop_b = (const float*)d_in[20];

  float* props   = (float*)d_out;
  float* af_reg  = props + (size_t)NA * 4;
  float* raw_reg = af_reg + (size_t)NA * 64;
  u16* Abf = (u16*)d_ws;               // [NA][64] bf16, in-place
  u16* S   = Abf + (size_t)NA * 64;    // [NA][64] bf16, in-place
  u16* T0  = S + (size_t)NA * 64;
  u16* T1  = T0 + (size_t)NA * 64;
  u16* WHp = T1 + (size_t)NA * 64;
  u16* WLp = WHp + 96256;

  k_prep<<<376, 256, 0, stream>>>(ae_w, msg_w1, msg_w2, upd_w1, upd_w2,
                                  fx_w1, fx_w2, WHp, WLp);

  int ngrid2 = (NA + 127) / 128;   // 2344 (2-group kernels)
  int ngrid4 = (NA + 255) / 256;   // 1172 (4-group FX kernel)
  k_embed_st<<<ngrid2, 256, 0, stream>>>(atom_fea, WHp, WLp, ae_b, msg_b1,
                                         Abf, S, T0);

  const int base0 = 6144, base1 = 6144 + 24576, base2 = 6144 + 2 * 24576;

  // layer 0: A,S in-place; T0 -> T1
  k_dense_mid<<<ngrid2, 256, 0, stream>>>(
      Abf, S, T0, nbr_idx, WHp, WLp,
      base0 + 8192, base0 + 12288, base0 + 20480, base1,
      msg_b2, upd_b1, upd_b2, msg_b1 + 64, T1);

  // layer 1: A,S in-place; T1 -> T0
  k_dense_mid<<<ngrid2, 256, 0, stream>>>(
      Abf, S, T1, nbr_idx, WHp, WLp,
      base1 + 8192, base1 + 12288, base1 + 20480, base2,
      msg_b2 + 64, upd_b1 + 64, upd_b2 + 64, msg_b1 + 128, T0);

  // layer 2 + fx: raw -> raw_reg (f32), af -> af_reg, props -> d_out
  k_dense_fx<<<ngrid4, 256, 0, stream>>>(
      Abf, S, T0, nbr_idx, WHp, WLp,
      base2 + 8192, base2 + 12288, base2 + 20480,
      msg_b2 + 128, upd_b1 + 128, upd_b2 + 128,
      fx_b1, fx_b2, prop_w, prop_b,
      raw_reg, af_reg, props);
}

// Round 18
// 507.134 us; speedup vs baseline: 1.2731x; 1.2731x over previous
//
#include <hip/hip_runtime.h>
#include <hip/hip_bf16.h>

// AtomicScaleModule — CGCNN GNN forward, MFMA bf16 activations x split-bf16
// weights. VERIFIED BEST (R14, 510us): gather-first, no fences, (256,2),
// bf16 A/S/T, A+S single-buffered in-place, T ping-pong, bf16 u16 transpose
// slab [32][74] (18.9 KB/block), rounded once on slab entry.
// Design-space map (all verified on HW): 2-group/wave regresses (R5,R17);
// (256,3) spills (R15); held-fragment restructure spills (R8/R9); split
// gather kernel regresses (R2); hoist+reuse neutral (R16).
//   a = X@AE + ae_b
//   per layer: s = a@MW1[0:64]+b1 ; t = a@MW1[64:128]   (fused into producer)
//              H = sum_c relu(s + t[idx])               (gather @ head of dense)
//              agg = H@MW2 + 12*b2
//              u1 = relu(a@UW1[0:64] + agg@UW1[64:128] + ub1)
//              a' = relu(a + u1@UW2 + ub2)  (+ fused s,t of next layer)
//   af = relu(a@FX1+fb1)@FX2+fb2 ; props = af@PW^T+pb   (fused into last dense)
// nbr_fea / ne_w / ne_b dead.

constexpr int NA = 300000;
constexpr int SCOL = 74;   // u16 cols: 4 groups x 18 (16 atoms + 2 pad), row 148B

typedef short          s16x8 __attribute__((ext_vector_type(8)));
typedef float          f32x4 __attribute__((ext_vector_type(4)));
typedef unsigned short u16;

#define DEVFN static __device__ __forceinline__

DEVFN u16 f2bf(float x) {
  unsigned u = __float_as_uint(x);
  u += 0x7fffu + ((u >> 16) & 1u);          // RTNE
  return (u16)(u >> 16);
}
DEVFN float bf2f(u16 h) { return __uint_as_float(((unsigned)h) << 16); }

// round 8 floats to bf16 fragment (v_cvt_pk_bf16_f32 pairs)
DEVFN s16x8 mk_hi(const float* v) {
  s16x8 hi;
#pragma unroll
  for (int i = 0; i < 8; i += 2) {
    __hip_bfloat162 h2 = __float22bfloat162_rn(make_float2(v[i], v[i + 1]));
    hi[i]     = (short)__bfloat16_as_ushort(h2.x);
    hi[i + 1] = (short)__bfloat16_as_ushort(h2.y);
  }
  return hi;
}

// 2-term MFMA: activation exact in bf16, weight split hi/lo
DEVFN f32x4 mf2(s16x8 ah, s16x8 bh, s16x8 bl, f32x4 c) {
  c = __builtin_amdgcn_mfma_f32_16x16x32_bf16(ah, bl, c, 0, 0, 0);
  c = __builtin_amdgcn_mfma_f32_16x16x32_bf16(ah, bh, c, 0, 0, 0);
  return c;
}

DEVFN void ldB(const u16* __restrict__ WH, const u16* __restrict__ WL,
               int seg, int kt, int ct, int CT, int l, s16x8& bh, s16x8& bl) {
  size_t o = (size_t)seg + ((size_t)((kt * CT + ct) * 64 + l)) * 8;
  bh = *(const s16x8*)(WH + o);
  bl = *(const s16x8*)(WL + o);
}

DEVFN f32x4 bias4(float bv) { f32x4 c; c[0] = bv; c[1] = bv; c[2] = bv; c[3] = bv; return c; }

// one 64x64 GEMM stage for all 4 groups: 8 B-pairs, 64 MFMA.
DEVFN void stage_mm(const u16* __restrict__ WH, const u16* __restrict__ WL,
                    int seg, int kt0, const s16x8 (&fh)[4][2],
                    int l, f32x4 (&cc)[4][4]) {
#pragma unroll
  for (int ct = 0; ct < 4; ++ct)
#pragma unroll
    for (int kt = 0; kt < 2; ++kt) {
      s16x8 bh, bl; ldB(WH, WL, seg, kt0 + kt, ct, 4, l, bh, bl);
#pragma unroll
      for (int gr = 0; gr < 4; ++gr)
        cc[gr][ct] = mf2(fh[gr][kt], bh, bl, cc[gr][ct]);
    }
}

// ---- bf16 slab transpose: half h covers features 32h..32h+31 --------------
// put: u16-typed stores ONLY (TBAA: u32 punning reorders vs u16 reads).
DEVFN void put_half_bf(u16 (*sl)[SCOL], int m, int g, const f32x4 (&cc)[4][4], int h) {
#pragma unroll
  for (int gr = 0; gr < 4; ++gr)
#pragma unroll
    for (int c = 0; c < 2; ++c) {
      f32x4 v = cc[gr][2 * h + c];
      __hip_bfloat162 p0 = __float22bfloat162_rn(make_float2(v[0], v[1]));
      __hip_bfloat162 p1 = __float22bfloat162_rn(make_float2(v[2], v[3]));
      u16* p = &sl[16 * c + m][gr * 18 + 4 * g];
      p[0] = __bfloat16_as_ushort(p0.x);
      p[1] = __bfloat16_as_ushort(p0.y);
      p[2] = __bfloat16_as_ushort(p1.x);
      p[3] = __bfloat16_as_ushort(p1.y);
    }
}
DEVFN s16x8 get_frag(const u16 (*sl)[SCOL], int m, int g, int gr) {
  s16x8 f;
#pragma unroll
  for (int i = 0; i < 8; ++i) f[i] = (short)sl[8 * g + i][gr * 18 + m];
  return f;
}
DEVFN void get_half_f32(const u16 (*sl)[SCOL], int m, int g, int gr, float* v) {
#pragma unroll
  for (int i = 0; i < 8; ++i) v[i] = bf2f(sl[8 * g + i][gr * 18 + m]);
}

DEVFN void trans_frags(u16 (*sl)[SCOL], int m, int g, const f32x4 (&cc)[4][4],
                       s16x8 (&fh)[4][2]) {
#pragma unroll
  for (int h = 0; h < 2; ++h) {
    put_half_bf(sl, m, g, cc, h);
#pragma unroll
    for (int gr = 0; gr < 4; ++gr) fh[gr][h] = get_frag(sl, m, g, gr);
  }
}

// store 64 bf16 per atom (S / T / A): u16 reads + shift-or packs, no cvt
DEVFN void trans_store_bf(u16 (*sl)[SCOL], int m, int g, const f32x4 (&cc)[4][4],
                          u16* __restrict__ B, const int (&nat)[4], const bool (&ok)[4]) {
#pragma unroll
  for (int h = 0; h < 2; ++h) {
    put_half_bf(sl, m, g, cc, h);
#pragma unroll
    for (int gr = 0; gr < 4; ++gr) {
      if (!ok[gr]) continue;
      int col = gr * 18 + m;
      uint4 q;
      unsigned* qp = (unsigned*)&q;
#pragma unroll
      for (int j = 0; j < 4; ++j)
        qp[j] = (unsigned)sl[8 * g + 2 * j][col] | ((unsigned)sl[8 * g + 2 * j + 1][col] << 16);
      *(uint4*)(B + (size_t)nat[gr] * 64 + 32 * h + 8 * g) = q;
    }
  }
}

DEVFN void pack_store8(u16* __restrict__ p, const float* v) {
  uint4 q;
  unsigned* qp = (unsigned*)&q;
#pragma unroll
  for (int i = 0; i < 4; ++i)
    qp[i] = (unsigned)f2bf(v[2 * i]) | ((unsigned)f2bf(v[2 * i + 1]) << 16);
  *(uint4*)p = q;
}

// ---- weight pre-conversion to B-frag layout (hi/lo bf16) ------------------
// Segments (entry offsets): AE 0 (96x64); per layer base=6144+l*24576:
//   MW1 +0 (128x64), MW2 +8192 (64x64), UW1 +12288 (128x64), UW2 +20480 (64x64)
// FX1 79872 (64x128), FX2 88064 (128x64). Total 96256 entries.
__global__ __launch_bounds__(256) void k_prep(
    const float* __restrict__ ae, const float* __restrict__ mw1,
    const float* __restrict__ mw2, const float* __restrict__ uw1,
    const float* __restrict__ uw2, const float* __restrict__ fx1,
    const float* __restrict__ fx2,
    u16* __restrict__ WH, u16* __restrict__ WL) {
  int e = blockIdx.x * 256 + threadIdx.x;
  const float* src;
  int K, N, loc;
  if (e < 6144) { src = ae; K = 92; N = 64; loc = e; }
  else if (e < 79872) {
    int r = e - 6144;
    int lyr = r / 24576, q = r % 24576;
    size_t l64 = (size_t)lyr * 64;
    if (q < 8192)       { src = mw1 + l64 * 128; K = 128; N = 64; loc = q; }
    else if (q < 12288) { src = mw2 + l64 * 64;  K = 64;  N = 64; loc = q - 8192; }
    else if (q < 20480) { src = uw1 + l64 * 128; K = 128; N = 64; loc = q - 12288; }
    else                { src = uw2 + l64 * 64;  K = 64;  N = 64; loc = q - 20480; }
  }
  else if (e < 88064) { src = fx1; K = 64;  N = 128; loc = e - 79872; }
  else if (e < 96256) { src = fx2; K = 128; N = 64;  loc = e - 88064; }
  else return;
  int k = (N == 64) ? (loc >> 6) : (loc >> 7);
  int j = loc & (N - 1);
  float v = (k < K) ? src[(size_t)k * N + j] : 0.f;
  u16 h = f2bf(v);
  int CT = N >> 4;
  int lane = ((k >> 3) & 3) * 16 + (j & 15);
  int fidx = (e - loc) + (((k >> 5) * CT + (j >> 4)) * 64 + lane) * 8 + (k & 7);
  WH[fidx] = h;
  WL[fidx] = f2bf(v - bf2f(h));
}

// ---- embed + s,t of layer 0 (64 atoms per wave) ---------------------------
__global__ __launch_bounds__(256, 2) void k_embed_st(
    const float* __restrict__ X,
    const u16* __restrict__ WH, const u16* __restrict__ WL,
    const float* __restrict__ aeb, const float* __restrict__ b1,
    u16* __restrict__ A, u16* __restrict__ S, u16* __restrict__ T) {
  __shared__ u16 slab[4][32][SCOL];
  int w = threadIdx.x >> 6, l = threadIdx.x & 63, m = l & 15, g = l >> 4;
  u16 (*sl)[SCOL] = slab[w];
  int nbase = blockIdx.x * 256 + w * 64;
  int nat[4]; bool ok[4];
#pragma unroll
  for (int gr = 0; gr < 4; ++gr) {
    nat[gr] = nbase + gr * 16 + m;
    ok[gr] = nat[gr] < NA;
    if (!ok[gr]) nat[gr] = NA - 1;
  }

  // a0 = X@AE + ae_b ; X fragments built per kt to bound liveness
  f32x4 ca[4][4];
#pragma unroll
  for (int gr = 0; gr < 4; ++gr)
#pragma unroll
    for (int ct = 0; ct < 4; ++ct) ca[gr][ct] = bias4(aeb[16 * ct + m]);
#pragma unroll
  for (int kt = 0; kt < 3; ++kt) {
    s16x8 xh[4];
#pragma unroll
    for (int gr = 0; gr < 4; ++gr) {
      const float* xr = X + (size_t)nat[gr] * 92;
      float v[8];
      if (kt < 2) {
        f32x4 a = *(const f32x4*)(xr + kt * 32 + g * 8);
        f32x4 b = *(const f32x4*)(xr + kt * 32 + g * 8 + 4);
        v[0]=a[0]; v[1]=a[1]; v[2]=a[2]; v[3]=a[3]; v[4]=b[0]; v[5]=b[1]; v[6]=b[2]; v[7]=b[3];
      } else if (g < 3) {
        f32x4 a = *(const f32x4*)(xr + 64 + g * 8);
        f32x4 b = *(const f32x4*)(xr + 64 + g * 8 + 4);
        v[0]=a[0]; v[1]=a[1]; v[2]=a[2]; v[3]=a[3]; v[4]=b[0]; v[5]=b[1]; v[6]=b[2]; v[7]=b[3];
      } else {
        f32x4 a = *(const f32x4*)(xr + 88);   // 88..91 valid, 92..95 pad
        v[0]=a[0]; v[1]=a[1]; v[2]=a[2]; v[3]=a[3]; v[4]=0.f; v[5]=0.f; v[6]=0.f; v[7]=0.f;
      }
      xh[gr] = mk_hi(v);
    }
#pragma unroll
    for (int ct = 0; ct < 4; ++ct) {
      s16x8 bh, bl; ldB(WH, WL, 0, kt, ct, 4, l, bh, bl);
#pragma unroll
      for (int gr = 0; gr < 4; ++gr)
        ca[gr][ct] = mf2(xh[gr], bh, bl, ca[gr][ct]);
    }
  }

  // transpose a0: store A (bf16) + build fragments from the same u16 reads
  s16x8 ah[4][2];
#pragma unroll
  for (int h = 0; h < 2; ++h) {
    put_half_bf(sl, m, g, ca, h);
#pragma unroll
    for (int gr = 0; gr < 4; ++gr) {
      int col = gr * 18 + m;
      u16 t8[8];
#pragma unroll
      for (int i = 0; i < 8; ++i) t8[i] = sl[8 * g + i][col];
      if (ok[gr]) {
        uint4 q;
        unsigned* qp = (unsigned*)&q;
#pragma unroll
        for (int j = 0; j < 4; ++j)
          qp[j] = (unsigned)t8[2 * j] | ((unsigned)t8[2 * j + 1] << 16);
        *(uint4*)(A + (size_t)nat[gr] * 64 + 32 * h + 8 * g) = q;
      }
      s16x8 f;
#pragma unroll
      for (int i = 0; i < 8; ++i) f[i] = (short)t8[i];
      ah[gr][h] = f;
    }
  }

  // s = a0@MW1[0:64] + b1  (stored bf16)
  f32x4 cs[4][4];
#pragma unroll
  for (int gr = 0; gr < 4; ++gr)
#pragma unroll
    for (int ct = 0; ct < 4; ++ct) cs[gr][ct] = bias4(b1[16 * ct + m]);
  stage_mm(WH, WL, 6144, 0, ah, l, cs);
  trans_store_bf(sl, m, g, cs, S, nat, ok);

  // t = a0@MW1[64:128]
  f32x4 cT[4][4];
#pragma unroll
  for (int gr = 0; gr < 4; ++gr)
#pragma unroll
    for (int ct = 0; ct < 4; ++ct) cT[gr][ct] = bias4(0.f);
  stage_mm(WH, WL, 6144, 2, ah, l, cT);
  trans_store_bf(sl, m, g, cT, T, nat, ok);
}

// ---- fused: gather + dense chain (+ next-layer s,t | + fx tail) -----------
// A and S are updated IN-PLACE (own-row read-then-write, race-free).
template <int HAS_NEXT, int HAS_FX>
__global__ __launch_bounds__(256, 2) void k_dense(
    u16* __restrict__ A, u16* __restrict__ S,
    const u16* __restrict__ T, const int* __restrict__ IDX,
    const u16* __restrict__ WH, const u16* __restrict__ WL,
    int segW2, int segU1, int segU2, int segWn,
    const float* __restrict__ b2, const float* __restrict__ ub1,
    const float* __restrict__ ub2, const float* __restrict__ bn,
    const float* __restrict__ fb1, const float* __restrict__ fb2,
    const float* __restrict__ PW, const float* __restrict__ PB,
    u16* __restrict__ Tout,
    float* __restrict__ RawOut, float* __restrict__ AF, float* __restrict__ PR) {
  __shared__ u16 slab[4][32][SCOL];
  int w = threadIdx.x >> 6, l = threadIdx.x & 63, m = l & 15, g = l >> 4;
  u16 (*sl)[SCOL] = slab[w];
  int nbase = blockIdx.x * 256 + w * 64;
  int nat[4]; bool ok[4];
#pragma unroll
  for (int gr = 0; gr < 4; ++gr) {
    nat[gr] = nbase + gr * 16 + m;
    ok[gr] = nat[gr] < NA;
    if (!ok[gr]) nat[gr] = NA - 1;
  }

  // gather FIRST: H = sum_c relu(s + t[idx]); loads issue at kernel entry.
  s16x8 hh[4][2];
#pragma unroll
  for (int gr = 0; gr < 4; ++gr) {
    const int* ip = IDX + (size_t)nat[gr] * 12;
    int4 i0 = *(const int4*)ip;
    int4 i1 = *(const int4*)(ip + 4);
    int4 i2 = *(const int4*)(ip + 8);
    int idxs[12] = {i0.x, i0.y, i0.z, i0.w, i1.x, i1.y, i1.z, i1.w,
                    i2.x, i2.y, i2.z, i2.w};
#pragma unroll
    for (int kt = 0; kt < 2; ++kt) {
      int f0 = 32 * kt + 8 * g;
      uint4 sv4 = *(const uint4*)(S + (size_t)nat[gr] * 64 + f0);
      float sv[8] = {
        bf2f((u16)(sv4.x & 0xffff)), bf2f((u16)(sv4.x >> 16)),
        bf2f((u16)(sv4.y & 0xffff)), bf2f((u16)(sv4.y >> 16)),
        bf2f((u16)(sv4.z & 0xffff)), bf2f((u16)(sv4.z >> 16)),
        bf2f((u16)(sv4.w & 0xffff)), bf2f((u16)(sv4.w >> 16))};
      float ha[8] = {0, 0, 0, 0, 0, 0, 0, 0};
#pragma unroll
      for (int c = 0; c < 12; ++c) {
        uint4 tv = *(const uint4*)(T + (size_t)idxs[c] * 64 + f0);
        ha[0] += fmaxf(sv[0] + bf2f((u16)(tv.x & 0xffff)), 0.f);
        ha[1] += fmaxf(sv[1] + bf2f((u16)(tv.x >> 16)), 0.f);
        ha[2] += fmaxf(sv[2] + bf2f((u16)(tv.y & 0xffff)), 0.f);
        ha[3] += fmaxf(sv[3] + bf2f((u16)(tv.y >> 16)), 0.f);
        ha[4] += fmaxf(sv[4] + bf2f((u16)(tv.z & 0xffff)), 0.f);
        ha[5] += fmaxf(sv[5] + bf2f((u16)(tv.z >> 16)), 0.f);
        ha[6] += fmaxf(sv[6] + bf2f((u16)(tv.w & 0xffff)), 0.f);
        ha[7] += fmaxf(sv[7] + bf2f((u16)(tv.w >> 16)), 0.f);
      }
      hh[gr][kt] = mk_hi(ha);
    }
  }

  // agg = H@W2 + 12*b2
  f32x4 cg[4][4];
#pragma unroll
  for (int gr = 0; gr < 4; ++gr)
#pragma unroll
    for (int ct = 0; ct < 4; ++ct) cg[gr][ct] = bias4(12.f * b2[16 * ct + m]);
  stage_mm(WH, WL, segW2, 0, hh, l, cg);

  // u1: a-part (bf16 A, straight loads), then agg-part
  f32x4 cu[4][4];
#pragma unroll
  for (int gr = 0; gr < 4; ++gr)
#pragma unroll
    for (int ct = 0; ct < 4; ++ct) cu[gr][ct] = bias4(ub1[16 * ct + m]);
  {
    s16x8 arh[4][2];
#pragma unroll
    for (int gr = 0; gr < 4; ++gr)
#pragma unroll
      for (int kt = 0; kt < 2; ++kt)
        arh[gr][kt] = *(const s16x8*)(A + (size_t)nat[gr] * 64 + kt * 32 + g * 8);
    stage_mm(WH, WL, segU1, 0, arh, l, cu);
  }
  {
    s16x8 qh[4][2];
    trans_frags(sl, m, g, cg, qh);
    stage_mm(WH, WL, segU1, 2, qh, l, cu);
  }
#pragma unroll
  for (int gr = 0; gr < 4; ++gr)
#pragma unroll
    for (int ct = 0; ct < 4; ++ct)
#pragma unroll
      for (int r = 0; r < 4; ++r) cu[gr][ct][r] = fmaxf(cu[gr][ct][r], 0.f);

  // upd = u1@U2 + ub2
  f32x4 cd[4][4];
#pragma unroll
  for (int gr = 0; gr < 4; ++gr)
#pragma unroll
    for (int ct = 0; ct < 4; ++ct) cd[gr][ct] = bias4(ub2[16 * ct + m]);
  {
    s16x8 uh[4][2];
    trans_frags(sl, m, g, cu, uh);
    stage_mm(WH, WL, segU2, 0, uh, l, cd);
  }

  // a' = relu(a + upd): transpose (bf16 slab), residual re-read (bf16,
  // L2-hot), store (bf16 in-place | f32 raw), fragments for next stages.
  s16x8 anh[4][2];
#pragma unroll
  for (int h = 0; h < 2; ++h) {
    put_half_bf(sl, m, g, cd, h);
#pragma unroll
    for (int gr = 0; gr < 4; ++gr) {
      float v[8];
      get_half_f32(sl, m, g, gr, v);
      uint4 au = *(const uint4*)(A + (size_t)nat[gr] * 64 + 32 * h + 8 * g);
      float av[8] = {
        bf2f((u16)(au.x & 0xffff)), bf2f((u16)(au.x >> 16)),
        bf2f((u16)(au.y & 0xffff)), bf2f((u16)(au.y >> 16)),
        bf2f((u16)(au.z & 0xffff)), bf2f((u16)(au.z >> 16)),
        bf2f((u16)(au.w & 0xffff)), bf2f((u16)(au.w >> 16))};
#pragma unroll
      for (int i = 0; i < 8; ++i) v[i] = fmaxf(v[i] + av[i], 0.f);
      if constexpr (HAS_FX) {
        if (ok[gr]) {
          float* p = RawOut + (size_t)nat[gr] * 64 + 32 * h + 8 * g;
          *(float4*)p = make_float4(v[0], v[1], v[2], v[3]);
          *(float4*)(p + 4) = make_float4(v[4], v[5], v[6], v[7]);
        }
      } else {
        if (ok[gr]) pack_store8(A + (size_t)nat[gr] * 64 + 32 * h + 8 * g, v);
      }
      if constexpr (HAS_NEXT || HAS_FX) anh[gr][h] = mk_hi(v);
    }
  }

  if constexpr (HAS_NEXT) {
    // s_next (bf16, in-place over S)
    f32x4 cs[4][4];
#pragma unroll
    for (int gr = 0; gr < 4; ++gr)
#pragma unroll
      for (int ct = 0; ct < 4; ++ct) cs[gr][ct] = bias4(bn[16 * ct + m]);
    stage_mm(WH, WL, segWn, 0, anh, l, cs);
    trans_store_bf(sl, m, g, cs, S, nat, ok);

    // t_next (bf16, ping-pong buffer)
    f32x4 cT[4][4];
#pragma unroll
    for (int gr = 0; gr < 4; ++gr)
#pragma unroll
      for (int ct = 0; ct < 4; ++ct) cT[gr][ct] = bias4(0.f);
    stage_mm(WH, WL, segWn, 2, anh, l, cT);
    trans_store_bf(sl, m, g, cT, Tout, nat, ok);
  }

  if constexpr (HAS_FX) {
    // af = relu(raw@FX1+fb1)@FX2+fb2, hidden 128 in two 64-col rounds
    f32x4 cf[4][4];
#pragma unroll
    for (int gr = 0; gr < 4; ++gr)
#pragma unroll
      for (int ct = 0; ct < 4; ++ct) cf[gr][ct] = bias4(fb2[16 * ct + m]);

#pragma unroll
    for (int hr = 0; hr < 2; ++hr) {
      f32x4 chh[4][4];
#pragma unroll
      for (int gr = 0; gr < 4; ++gr)
#pragma unroll
        for (int ct = 0; ct < 4; ++ct)
          chh[gr][ct] = bias4(fb1[16 * (4 * hr + ct) + m]);
#pragma unroll
      for (int ct = 0; ct < 4; ++ct)
#pragma unroll
        for (int kt = 0; kt < 2; ++kt) {
          s16x8 bh, bl; ldB(WH, WL, 79872, kt, 4 * hr + ct, 8, l, bh, bl);
#pragma unroll
          for (int gr = 0; gr < 4; ++gr)
            chh[gr][ct] = mf2(anh[gr][kt], bh, bl, chh[gr][ct]);
        }
#pragma unroll
      for (int gr = 0; gr < 4; ++gr)
#pragma unroll
        for (int ct = 0; ct < 4; ++ct)
#pragma unroll
          for (int r = 0; r < 4; ++r) chh[gr][ct][r] = fmaxf(chh[gr][ct][r], 0.f);

      s16x8 hfh[4][2];
      trans_frags(sl, m, g, chh, hfh);
      stage_mm(WH, WL, 88064, 2 * hr, hfh, l, cf);
    }

    // AF store + props partials in the same A-layout pass
    float pp[4][4];
#pragma unroll
    for (int gr = 0; gr < 4; ++gr)
#pragma unroll
      for (int p = 0; p < 4; ++p) pp[gr][p] = 0.f;
#pragma unroll
    for (int h = 0; h < 2; ++h) {
      put_half_bf(sl, m, g, cf, h);
      f32x4 pw0[4], pw1[4];
#pragma unroll
      for (int p = 0; p < 4; ++p) {
        const float* q = PW + p * 64 + 32 * h + 8 * g;
        pw0[p] = *(const f32x4*)q;
        pw1[p] = *(const f32x4*)(q + 4);
      }
#pragma unroll
      for (int gr = 0; gr < 4; ++gr) {
        float v[8];
        get_half_f32(sl, m, g, gr, v);
        if (ok[gr]) {
          float* p = AF + (size_t)nat[gr] * 64 + 32 * h + 8 * g;
          *(float4*)p = make_float4(v[0], v[1], v[2], v[3]);
          *(float4*)(p + 4) = make_float4(v[4], v[5], v[6], v[7]);
        }
#pragma unroll
        for (int p = 0; p < 4; ++p)
#pragma unroll
          for (int i = 0; i < 4; ++i)
            pp[gr][p] += v[i] * pw0[p][i] + v[i + 4] * pw1[p][i];
      }
    }
    // reduce over g lanes (l^16, l^32), then lane (m,g) writes prop p=g
#pragma unroll
    for (int gr = 0; gr < 4; ++gr) {
      float r0 = pp[gr][0], r1 = pp[gr][1], r2 = pp[gr][2], r3 = pp[gr][3];
      r0 += __shfl_xor(r0, 16); r0 += __shfl_xor(r0, 32);
      r1 += __shfl_xor(r1, 16); r1 += __shfl_xor(r1, 32);
      r2 += __shfl_xor(r2, 16); r2 += __shfl_xor(r2, 32);
      r3 += __shfl_xor(r3, 16); r3 += __shfl_xor(r3, 32);
      float sel = (g == 0) ? r0 : (g == 1) ? r1 : (g == 2) ? r2 : r3;
      if (ok[gr]) PR[(size_t)nat[gr] * 4 + g] = sel + PB[g];
    }
  }
}

extern "C" void kernel_launch(void* const* d_in, const int* in_sizes, int n_in,
                              void* d_out, int out_size, void* d_ws, size_t ws_size,
                              hipStream_t stream) {
  const float* atom_fea = (const float*)d_in[0];
  const int*   nbr_idx  = (const int*)d_in[2];
  const float* ae_w   = (const float*)d_in[3];
  const float* ae_b   = (const float*)d_in[4];
  const float* msg_w1 = (const float*)d_in[7];
  const float* msg_b1 = (const float*)d_in[8];
  const float* msg_w2 = (const float*)d_in[9];
  const float* msg_b2 = (const float*)d_in[10];
  const float* upd_w1 = (const float*)d_in[11];
  const float* upd_b1 = (const float*)d_in[12];
  const float* upd_w2 = (const float*)d_in[13];
  const float* upd_b2 = (const float*)d_in[14];
  const float* fx_w1  = (const float*)d_in[15];
  const float* fx_b1  = (const float*)d_in[16];
  const float* fx_w2  = (const float*)d_in[17];
  const float* fx_b2  = (const float*)d_in[18];
  const float* prop_w = (const float*)d_in[19];
  const float* prop_b = (const float*)d_in[20];

  float* props   = (float*)d_out;
  float* af_reg  = props + (size_t)NA * 4;
  float* raw_reg = af_reg + (size_t)NA * 64;
  u16* Abf = (u16*)d_ws;               // [NA][64] bf16, in-place
  u16* S   = Abf + (size_t)NA * 64;    // [NA][64] bf16, in-place
  u16* T0  = S + (size_t)NA * 64;
  u16* T1  = T0 + (size_t)NA * 64;
  u16* WHp = T1 + (size_t)NA * 64;
  u16* WLp = WHp + 96256;

  k_prep<<<376, 256, 0, stream>>>(ae_w, msg_w1, msg_w2, upd_w1, upd_w2,
                                  fx_w1, fx_w2, WHp, WLp);

  int ngrid = (NA + 255) / 256;   // 1172
  k_embed_st<<<ngrid, 256, 0, stream>>>(atom_fea, WHp, WLp, ae_b, msg_b1,
                                        Abf, S, T0);

  const int base0 = 6144, base1 = 6144 + 24576, base2 = 6144 + 2 * 24576;

  // layer 0: A,S in-place; T0 -> T1
  k_dense<1, 0><<<ngrid, 256, 0, stream>>>(
      Abf, S, T0, nbr_idx, WHp, WLp,
      base0 + 8192, base0 + 12288, base0 + 20480, base1,
      msg_b2, upd_b1, upd_b2, msg_b1 + 64,
      fx_b1, fx_b2, prop_w, prop_b,
      T1, nullptr, nullptr, nullptr);

  // layer 1: A,S in-place; T1 -> T0
  k_dense<1, 0><<<ngrid, 256, 0, stream>>>(
      Abf, S, T1, nbr_idx, WHp, WLp,
      base1 + 8192, base1 + 12288, base1 + 20480, base2,
      msg_b2 + 64, upd_b1 + 64, upd_b2 + 64, msg_b1 + 128,
      fx_b1, fx_b2, prop_w, prop_b,
      T0, nullptr, nullptr, nullptr);

  // layer 2 + fx: raw -> raw_reg (f32), af -> af_reg, props -> d_out
  k_dense<0, 1><<<ngrid, 256, 0, stream>>>(
      Abf, S, T0, nbr_idx, WHp, WLp,
      base2 + 8192, base2 + 12288, base2 + 20480, 0,
      msg_b2 + 128, upd_b1 + 128, upd_b2 + 128, msg_b1,
      fx_b1, fx_b2, prop_w, prop_b,
      T1, raw_reg, af_reg, props);
}